// Round 26
// baseline (85.642 us; speedup 1.0000x reference)
//
#include <hip/hip_runtime.h>

#define BTOT 65536
#define TST  28
#define PACK_DW 208
// per-lane dwords: [0..128) w2b(nt,ks) | [128..160) wx(nt,ks2)
//                  [160..192) w3(ks)   | [192..208) b3 (f32, D rows)
// ws: [0 .. 64*208) frags | [WXL_OFF ..) WxL 32x128 f32 (rows 29..31 zeroed)
#define WXL_OFF (64 * PACK_DW)

typedef __attribute__((ext_vector_type(8)))  short bf16x8;
typedef __attribute__((ext_vector_type(4)))  float f32x4;
typedef __attribute__((ext_vector_type(16))) float f32x16;
typedef __attribute__((ext_vector_type(4)))  unsigned int u32x4;

__device__ __forceinline__ unsigned int f2bf(float f) {
    unsigned u = __float_as_uint(f);
    u += 0x7fff + ((u >> 16) & 1);   // RNE
    return u >> 16;
}
__device__ __forceinline__ unsigned int pk2bf(float a, float b) {
    return f2bf(a) | (f2bf(b) << 16);
}
__device__ __forceinline__ bf16x8 cvt8(f32x4 a, f32x4 b) {
    union { unsigned int u[4]; bf16x8 v; } r;
    asm("v_cvt_pk_bf16_f32 %0, %1, %2" : "=v"(r.u[0]) : "v"(a[0]), "v"(a[1]));
    asm("v_cvt_pk_bf16_f32 %0, %1, %2" : "=v"(r.u[1]) : "v"(a[2]), "v"(a[3]));
    asm("v_cvt_pk_bf16_f32 %0, %1, %2" : "=v"(r.u[2]) : "v"(b[0]), "v"(b[1]));
    asm("v_cvt_pk_bf16_f32 %0, %1, %2" : "=v"(r.u[3]) : "v"(b[2]), "v"(b[3]));
    return r.v;
}

// 32x32x16 sigma (derivation in r26 notes, 2 samples hand-verified):
// acc tile nt, reg-pair p (regs 2p,2p+1) -> cvt_pk dword at B-frag
// ks = 2nt + (p>>2), jd = p&3. The h-unit consumed at A/B k-slot (ks,hi,j) is
//   s(ks,hi,j) = 16ks + 8*(j>>2) + 4hi + 2*((j>>1)&1) + (j&1)
// so W2b/W3 A-frags are packed with row index s; D-rows keep identity labels
// (unit = 32nt + rowD), so relu/bias/epilogue semantics are unchanged.

// pack1: blocks 0..28 compute WxL row k (Wx = W1@W2a; row 28 = b2 + b1@W2a,
// hit by x-frag col 28 := 1.0; block 28 zeroes rows 29..31). Block 29 packs
// sigma-permuted W2b A-frags; block 30 packs sigma-permuted W3 frags + b3.
__global__ void pack1(const float* __restrict__ W1, const float* __restrict__ b1,
                      const float* __restrict__ W2, const float* __restrict__ b2,
                      const float* __restrict__ W3, const float* __restrict__ b3,
                      unsigned int* __restrict__ ws) {
    float* WxL = (float*)(ws + WXL_OFF);
    const int bid = blockIdx.x, tid = threadIdx.x;
    if (bid < 29) {
        const int k = bid, n = tid;   // 128 threads
        float s = 0.f;
        if (k < 28) {
            for (int m = 0; m < 128; ++m) s += W1[k * 128 + m] * W2[m * 128 + n];
        } else {
            s = b2[n];
            for (int m = 0; m < 128; ++m) s += b1[m] * W2[m * 128 + n];
        }
        WxL[k * 128 + n] = s;
        if (k == 28) { WxL[29*128+n] = 0.f; WxL[30*128+n] = 0.f; WxL[31*128+n] = 0.f; }
    } else if (bid == 29) {
        if (tid < 64) {
            const int hi = tid >> 5, ln = tid & 31;
            unsigned int* P = ws + tid * PACK_DW;
            for (int nt = 0; nt < 4; ++nt)
                for (int ks = 0; ks < 8; ++ks)
                    for (int jd = 0; jd < 4; ++jd) {
                        const int s = 16 * ks + 8 * (jd >> 1) + 4 * hi + 2 * (jd & 1);
                        const int n = 32 * nt + ln;
                        P[(nt * 8 + ks) * 4 + jd] =
                            pk2bf(W2[(128 + s) * 128 + n], W2[(129 + s) * 128 + n]);
                    }
        }
    } else {
        if (tid < 64) {
            const int hi = tid >> 5, ln = tid & 31;
            unsigned int* P = ws + tid * PACK_DW;
            for (int ks = 0; ks < 8; ++ks)
                for (int jd = 0; jd < 4; ++jd) {
                    const int s = 16 * ks + 8 * (jd >> 1) + 4 * hi + 2 * (jd & 1);
                    float lo = (ln < 10) ? W3[s * 10 + ln] : 0.f;
                    float hh = (ln < 10) ? W3[(s + 1) * 10 + ln] : 0.f;
                    P[160 + ks * 4 + jd] = pk2bf(lo, hh);
                }
            for (int r = 0; r < 16; ++r) {
                const int row = (r & 3) + 8 * (r >> 2) + 4 * hi;
                P[192 + r] = __float_as_uint((row < 10) ? b3[row] : 0.f);
            }
        }
    }
}

// pack2: wx A-frags (natural k order — x's B-frag is packed naturally).
__global__ void pack2(unsigned int* __restrict__ ws) {
    const int tid = threadIdx.x;
    if (tid < 64) {
        const float* WxL = (const float*)(ws + WXL_OFF);
        const int hi = tid >> 5, ln = tid & 31;
        unsigned int* P = ws + tid * PACK_DW;
        for (int nt = 0; nt < 4; ++nt)
            for (int ks2 = 0; ks2 < 2; ++ks2)
                for (int jd = 0; jd < 4; ++jd) {
                    const int k = 16 * ks2 + 8 * hi + 2 * jd;
                    const int n = 32 * nt + ln;
                    P[128 + (nt * 2 + ks2) * 4 + jd] =
                        pk2bf(WxL[k * 128 + n], WxL[(k + 1) * 128 + n]);
                }
    }
}

#define MFMA32(a, b, c) __builtin_amdgcn_mfma_f32_32x32x16_bf16(a, b, c, 0, 0, 0)

// ZERO-LDS-feedback recurrence on 32x32x16: 1 wave / 32 batch rows / all 128 n.
// Per step: 8 x-MFMAs + 32 h-MFMAs = 40 instrs for 32 rows (r23: 80 per 32).
// The r17-25 plateau is per-wave MFMA issue cadence (~38.5 cyc/slot at 2
// waves/SIMD) — halving instruction count at 2x FLOP/instr attacks it head-on.
// wx frags live in block-private LDS (1-wave block: no barrier) to fit 2
// waves/SIMD. h feedback is register-only via the 32x32 sigma (above).
__global__ __launch_bounds__(64, 2) void rnn_kernel(
    const float* __restrict__ x, const unsigned int* __restrict__ wsPack,
    float* __restrict__ out)
{
    __shared__ __align__(16) unsigned int wxLds[8 * 64 * 4];   // 8 KB
    const int lane = threadIdx.x;
    const int hi = lane >> 5, ln = lane & 31;
    const int r0 = blockIdx.x * 32;

    const unsigned int* P = wsPack + lane * PACK_DW;
    bf16x8 w2b[4][8];
    #pragma unroll
    for (int nt = 0; nt < 4; ++nt)
        #pragma unroll
        for (int ks = 0; ks < 8; ++ks)
            w2b[nt][ks] = *(const bf16x8*)(P + (nt * 8 + ks) * 4);
    // wx frags -> LDS (one-time; in-wave ordering suffices)
    #pragma unroll
    for (int f = 0; f < 8; ++f) {
        u32x4 v = *(const u32x4*)(P + 128 + f * 4);
        *(u32x4*)&wxLds[(f * 64 + lane) * 4] = v;
    }

    // x B-frags: frag ks2 elem j = x[r0+ln][28t + 16ks2 + 8hi + j].
    // hi==1 frag1 upper half = {1.0 (col 28 bias hook), 0,0,0}.
    const f32x4 onec = {1.f, 0.f, 0.f, 0.f};
    const float* xr = x + (size_t)(r0 + ln) * 784;
    f32x4 q0 = *(const f32x4*)(xr + 8 * hi);
    f32x4 q1 = *(const f32x4*)(xr + 8 * hi + 4);
    f32x4 q2 = *(const f32x4*)(xr + 16 + 8 * hi);
    f32x4 q3 = (hi == 0) ? *(const f32x4*)(xr + 20) : onec;
    bf16x8 xb0 = cvt8(q0, q1);
    bf16x8 xb1 = cvt8(q2, q3);
    const f32x16 z16 = {0.f,0.f,0.f,0.f,0.f,0.f,0.f,0.f,0.f,0.f,0.f,0.f,0.f,0.f,0.f,0.f};

    f32x16 acc[4];
    union HF { unsigned int u[4]; bf16x8 v; } hbF[8];
    f32x4 n0, n1, n2, n3;

// relu + pack tile NT's reg pair P8 -> hbF[2*NT + (P8>>2)].u[P8&3]
#define CVT1(NT, P8) do {                                                   \
        float a0 = fmaxf(acc[NT][2 * (P8)],     0.f);                       \
        float a1 = fmaxf(acc[NT][2 * (P8) + 1], 0.f);                       \
        unsigned d;                                                         \
        asm("v_cvt_pk_bf16_f32 %0, %1, %2" : "=v"(d) : "v"(a0), "v"(a1));   \
        hbF[2 * (NT) + ((P8) >> 2)].u[(P8) & 3] = d;                        \
    } while (0)
#define CVTTILE(NT) CVT1(NT,0); CVT1(NT,1); CVT1(NT,2); CVT1(NT,3); \
                    CVT1(NT,4); CVT1(NT,5); CVT1(NT,6); CVT1(NT,7)
#define CVTALL CVTTILE(0); CVTTILE(1); CVTTILE(2); CVTTILE(3)

    // ---- step 0: h0 == 0, x part only (exact) ----
    {
        const float* xp = xr + 28;
        n0 = *(const f32x4*)(xp + 8 * hi);
        n1 = *(const f32x4*)(xp + 8 * hi + 4);
        n2 = *(const f32x4*)(xp + 16 + 8 * hi);
        n3 = (hi == 0) ? *(const f32x4*)(xp + 20) : onec;
        #pragma unroll
        for (int nt = 0; nt < 4; ++nt) {
            bf16x8 wa = *(const bf16x8*)&wxLds[((nt * 2) * 64 + lane) * 4];
            bf16x8 wb = *(const bf16x8*)&wxLds[((nt * 2 + 1) * 64 + lane) * 4];
            acc[nt] = MFMA32(wa, xb0, z16);
            acc[nt] = MFMA32(wb, xb1, acc[nt]);
        }
        xb0 = cvt8(n0, n1);
        xb1 = cvt8(n2, n3);
        CVTALL;
    }

    // ---- steps 1..27 ----
    #pragma unroll 2
    for (int t = 1; t < TST; ++t) {
        const bool pf = (t + 1 < TST);
        if (pf) {
            const float* xp = xr + (t + 1) * 28;
            n0 = *(const f32x4*)(xp + 8 * hi);
            n1 = *(const f32x4*)(xp + 8 * hi + 4);
            n2 = *(const f32x4*)(xp + 16 + 8 * hi);
            n3 = (hi == 0) ? *(const f32x4*)(xp + 20) : onec;
        }
        __builtin_amdgcn_s_setprio(1);
        // x-part (wx streamed from LDS — frees 32 VGPRs for 2-wave residency)
        #pragma unroll
        for (int nt = 0; nt < 4; ++nt) {
            bf16x8 wa = *(const bf16x8*)&wxLds[((nt * 2) * 64 + lane) * 4];
            bf16x8 wb = *(const bf16x8*)&wxLds[((nt * 2 + 1) * 64 + lane) * 4];
            acc[nt] = MFMA32(wa, xb0, z16);
            acc[nt] = MFMA32(wb, xb1, acc[nt]);
        }
        // h-part: ks-outer, nt-inner (consecutive instrs independent)
        #pragma unroll
        for (int ks = 0; ks < 8; ++ks)
            #pragma unroll
            for (int nt = 0; nt < 4; ++nt)
                acc[nt] = MFMA32(w2b[nt][ks], hbF[ks].v, acc[nt]);
        __builtin_amdgcn_s_setprio(0);
        if (pf) {
            xb0 = cvt8(n0, n1);
            xb1 = cvt8(n2, n3);
        }
        CVTALL;   // registers ARE next step's B-frags (sigma)
    }

    // epilogue: out^T = W3^T . h_final^T + b3 — hbF holds h_final
    bf16x8 w3f[8];
    #pragma unroll
    for (int ks = 0; ks < 8; ++ks) w3f[ks] = *(const bf16x8*)(P + 160 + ks * 4);
    const float* bp = (const float*)(P + 192);
    f32x16 accO;
    #pragma unroll
    for (int r = 0; r < 16; ++r) accO[r] = bp[r];
    #pragma unroll
    for (int ks = 0; ks < 8; ++ks)
        accO = MFMA32(w3f[ks], hbF[ks].v, accO);
    float* op = out + (size_t)(r0 + ln) * 10;
    #pragma unroll
    for (int r = 0; r < 16; ++r) {
        const int row = (r & 3) + 8 * (r >> 2) + 4 * hi;
        if (row < 10) op[row] = accO[r];
    }

#undef CVT1
#undef CVTTILE
#undef CVTALL
}

extern "C" void kernel_launch(void* const* d_in, const int* in_sizes, int n_in,
                              void* d_out, int out_size, void* d_ws, size_t ws_size,
                              hipStream_t stream) {
    const float* x  = (const float*)d_in[0];
    const float* W1 = (const float*)d_in[1];
    const float* b1 = (const float*)d_in[2];
    const float* W2 = (const float*)d_in[3];
    const float* b2 = (const float*)d_in[4];
    const float* W3 = (const float*)d_in[5];
    const float* b3 = (const float*)d_in[6];
    unsigned int* ws = (unsigned int*)d_ws;   // 17408 dwords = 68 KiB

    pack1<<<31, 128, 0, stream>>>(W1, b1, W2, b2, W3, b3, ws);
    pack2<<<1, 64, 0, stream>>>(ws);
    rnn_kernel<<<BTOT / 32, 64, 0, stream>>>(x, ws, (float*)d_out);
}